// Round 1
// baseline (101.873 us; speedup 1.0000x reference)
//
#include <hip/hip_runtime.h>

#define ROWS 4096
#define COLS 2048
#define NLEV 16
#define TEMP 100.0f
#define EPS  1e-6f
#define LOG2E 1.4426950408889634f
// geometric ratio between adjacent levels: exp(-100/15)
#define RGEO 1.2726338e-3f
#define C2P  1.2710160e-3f           // RGEO/(1+RGEO)
#define C1PP (1.0f + 2.0f * C2P)     // coefficient of uv in dq

#define TPB 256            // threads per block = columns per block
#define RPB 64             // rows per block
#define RBLKS (ROWS / RPB) // 64 row-blocks
#define UNROLL 8
#define RTPB 128           // reduce threads per block

typedef _Float16 half8_t __attribute__((ext_vector_type(8)));
typedef _Float16 half2_t __attribute__((ext_vector_type(2)));

// d_ws: _Float16 partial[RBLKS][COLS][NLEV] = 4.2 MB
//
// Suffix-sum binning in PACKED f16 with the VOP3P clamp bit forced via
// inline asm:  d = v_pk_add_f16(P2, A2[i]) clamp  ==  clamp01(Pr+1-l)
// for the level pair (2i, 2i+1); A2[i] = {1-2i, -2i} folds the +1.
// G2 is flushed to f32 every UNROLL rows so f16 rounding never
// accumulates past 8 values. bin[l] = G[l]-G[l+1] recovers the split.

__global__ __launch_bounds__(TPB) void quant_main_kernel(
    const float* __restrict__ weight,
    const float* __restrict__ w_min,
    const float* __restrict__ w_max,
    float* __restrict__ dequant,
    _Float16* __restrict__ partial,
    float* __restrict__ out_ent)
{
    const int t  = threadIdx.x;
    const int c  = blockIdx.x * TPB + t;     // column (coalesced)
    const int r0 = blockIdx.y * RPB;

    // zero the entropy accumulator (stream-ordered before reduce kernel)
    if (blockIdx.x == 0 && blockIdx.y == 0 && t == 0) out_ent[0] = 0.0f;

    const float wmin = w_min[c];
    const float wmax = w_max[c];
    const float mn   = fminf(wmin, wmax - EPS);       // w_min_c
    const float mx   = fmaxf(wmax, mn + EPS);         // w_max_c
    const float rng  = mx - mn;
    const float inv_rng = __builtin_amdgcn_rcpf(rng + EPS);

    const float S     = (TEMP / 15.0f) * LOG2E;       // level spacing, exp2 units
    const float s15   = 15.0f * inv_rng;              // y = (w-mn)*s15 in (0,15)
    const float b15   = -mn * s15;
    const float rng15 = rng * (1.0f / 15.0f);

    // f32 suffix-sum accumulators (flushed from f16 each batch)
    float gacc[NLEV];
#pragma unroll
    for (int l = 0; l < NLEV; ++l) gacc[l] = 0.0f;

    // level constants {1-2i, -2i}, pinned in VGPRs (block remat inside loop)
    half2_t A2[8];
#pragma unroll
    for (int i = 0; i < 8; ++i) {
        A2[i] = (half2_t){(_Float16)(1 - 2 * i), (_Float16)(-2 * i)};
        asm("" : "+v"(A2[i]));
    }

    const float* __restrict__ wp = weight  + (size_t)r0 * COLS + c;
    float* __restrict__       dq = dequant + (size_t)r0 * COLS + c;

    // prologue: first batch of loads in flight
    float w[UNROLL];
#pragma unroll
    for (int j = 0; j < UNROLL; ++j)
        w[j] = __builtin_nontemporal_load(&wp[(size_t)j * COLS]);

    for (int r = 0; r < RPB; r += UNROLL) {
        // depth-1 prefetch: next batch issues before this batch's compute
        float wn[UNROLL];
        const bool more = (r + UNROLL) < RPB;
        if (more) {
#pragma unroll
            for (int j = 0; j < UNROLL; ++j)
                wn[j] = __builtin_nontemporal_load(
                    &wp[(size_t)(r + UNROLL + j) * COLS]);
        }

        half2_t G2[8];
#pragma unroll
        for (int i = 0; i < 8; ++i) G2[i] = (half2_t){(_Float16)0, (_Float16)0};

#pragma unroll
        for (int j = 0; j < UNROLL; ++j) {
            const float y  = fmaf(w[j], s15, b15);    // in (0,15)
            float kf = floorf(y);
            kf = fminf(fmaxf(kf, 0.0f), 14.0f);       // v_med3

            const float q  = fmaf(y - kf, 2.0f * S, -S);   // (2f-S), exp2 units
            const float e  = __builtin_amdgcn_exp2f(q);
            const float uv = e * __builtin_amdgcn_rcpf(1.0f + e);  // u/(t+u)

            // dq = (kf - C2P + uv*C1PP)*rng15 + mn  (phantom +/-1 folded)
            __builtin_nontemporal_store(
                fmaf(fmaf(uv, C1PP, kf - C2P), rng15, mn),
                &dq[(size_t)(r + j) * COLS]);

            const float Pr = kf + uv;                 // (the +1 lives in A2)
            const _Float16 Ph = (_Float16)Pr;
            const half2_t P2 = {Ph, Ph};
#pragma unroll
            for (int i = 0; i < 8; ++i) {
                half2_t d;
                // d = clamp01(P2 + A2[i])  -- one VOP3P with clamp bit
                asm("v_pk_add_f16 %0, %1, %2 clamp"
                    : "=v"(d) : "v"(P2), "v"(A2[i]));
                G2[i] += d;                           // v_pk_add_f16
            }
        }

        // flush f16 suffix sums into f32 (max 8 values accumulated in f16)
#pragma unroll
        for (int l = 0; l < NLEV; ++l) gacc[l] += (float)G2[l >> 1][l & 1];

        if (more) {
#pragma unroll
            for (int j = 0; j < UNROLL; ++j) w[j] = wn[j];
        }
    }

    // difference the suffix sums -> bins, store fp16 partials
    float g[NLEV + 1];
#pragma unroll
    for (int l = 0; l < NLEV; ++l) g[l] = gacc[l];
    g[NLEV] = 0.0f;

    half8_t v0, v1;
#pragma unroll
    for (int l = 0; l < NLEV; ++l) {
        const float bin = g[l] - g[l + 1];
        if (l < 8) v0[l] = (_Float16)bin; else v1[l - 8] = (_Float16)bin;
    }
    half8_t* pp = (half8_t*)(partial + ((size_t)blockIdx.y * COLS + c) * NLEV);
    pp[0] = v0;
    pp[1] = v1;
}

// fused reduce + entropy: one thread per (col, level-pair) = 16384 threads,
// 128 blocks x 128 threads. 8 consecutive lanes own one column -> shuffle.
__global__ __launch_bounds__(RTPB) void reduce_entropy_kernel(
    const _Float16* __restrict__ partial,
    float* __restrict__ out_ent)
{
    __shared__ float red[RTPB];
    const int i = blockIdx.x * RTPB + threadIdx.x;   // [0, COLS*NLEV/2)
    const half2_t* p2 = (const half2_t*)partial;

    float m0 = 0.0f, m1 = 0.0f;
#pragma unroll 16
    for (int rb = 0; rb < RBLKS; ++rb) {
        const half2_t v = p2[(size_t)rb * (COLS * NLEV / 2) + i];
        m0 += (float)v[0];
        m1 += (float)v[1];
    }

    float tot = m0 + m1;
    tot += __shfl_xor(tot, 1);
    tot += __shfl_xor(tot, 2);
    tot += __shfl_xor(tot, 4);          // column total across the 8-lane group
    const float inv = __builtin_amdgcn_rcpf(tot + EPS);

    const float p0 = m0 * inv;
    const float p1 = m1 * inv;
    float ent = -(p0 * __logf(p0 + EPS) + p1 * __logf(p1 + EPS));

    red[threadIdx.x] = ent;
    __syncthreads();
#pragma unroll
    for (int off = RTPB / 2; off > 0; off >>= 1) {
        if (threadIdx.x < off) red[threadIdx.x] += red[threadIdx.x + off];
        __syncthreads();
    }
    if (threadIdx.x == 0) atomicAdd(out_ent, red[0]);   // 128 atomics total
}

extern "C" void kernel_launch(void* const* d_in, const int* in_sizes, int n_in,
                              void* d_out, int out_size, void* d_ws, size_t ws_size,
                              hipStream_t stream)
{
    const float* weight = (const float*)d_in[0];
    const float* w_min  = (const float*)d_in[1];
    const float* w_max  = (const float*)d_in[2];

    float* out     = (float*)d_out;
    float* dequant = out;                          // ROWS*COLS floats
    float* out_ent = out + (size_t)ROWS * COLS;    // 1 float
    _Float16* partial = (_Float16*)d_ws;           // RBLKS*COLS*NLEV halves

    quant_main_kernel<<<dim3(COLS / TPB, RBLKS), TPB, 0, stream>>>(
        weight, w_min, w_max, dequant, partial, out_ent);

    reduce_entropy_kernel<<<(COLS * NLEV / 2) / RTPB, RTPB, 0, stream>>>(
        partial, out_ent);
}

// Round 2
// 95.451 us; speedup vs baseline: 1.0673x; 1.0673x over previous
//
#include <hip/hip_runtime.h>

#define ROWS 4096
#define COLS 2048
#define NLEV 16
#define TEMP 100.0f
#define EPS  1e-6f
#define LOG2E 1.4426950408889634f
// geometric ratio between adjacent levels: exp(-100/15)
#define RGEO 1.2726338e-3f
#define C2P  1.2710160e-3f           // RGEO/(1+RGEO)
#define C1PP (1.0f + 2.0f * C2P)     // coefficient of uv in dq

#define TPB 256            // threads per block = columns per block
#define RPB 32             // rows per block
#define RBLKS (ROWS / RPB) // 128 row-blocks
#define UNROLL 8

typedef _Float16 half8_t __attribute__((ext_vector_type(8)));
typedef _Float16 half2_t __attribute__((ext_vector_type(2)));

// d_ws: _Float16 partial[RBLKS][COLS][NLEV] = 8.4 MB
//
// Suffix-sum binning in PACKED f16 with the VOP3P clamp bit forced via
// inline asm:  d = v_pk_add_f16(P2, A2[i]) clamp  ==  clamp01(Pr+1-l)
// for the level pair (2i, 2i+1); A2[i] = {1-2i, -2i} folds the +1.
// 2 instructions per level pair -> 16 pk instr/element, no LDS, no
// dynamic indexing. bin[l] = G[l]-G[l+1] recovers tv/uv split binning.
//
// NOTE: weight loads are PLAIN (not nontemporal) — the 33.5 MB input is
// Infinity-Cache-resident across bench iterations; NT loads bypass it
// and cost ~2x latency (measured regression in R1).

__global__ __launch_bounds__(TPB) void quant_main_kernel(
    const float* __restrict__ weight,
    const float* __restrict__ w_min,
    const float* __restrict__ w_max,
    float* __restrict__ dequant,
    _Float16* __restrict__ partial,
    float* __restrict__ out_ent)
{
    const int t  = threadIdx.x;
    const int c  = blockIdx.x * TPB + t;     // column (coalesced)
    const int r0 = blockIdx.y * RPB;

    // zero the entropy accumulator (stream-ordered before reduce kernel)
    if (blockIdx.x == 0 && blockIdx.y == 0 && t == 0) out_ent[0] = 0.0f;

    const float wmin = w_min[c];
    const float wmax = w_max[c];
    const float mn   = fminf(wmin, wmax - EPS);       // w_min_c
    const float mx   = fmaxf(wmax, mn + EPS);         // w_max_c
    const float rng  = mx - mn;
    const float inv_rng = __builtin_amdgcn_rcpf(rng + EPS);

    const float S     = (TEMP / 15.0f) * LOG2E;       // level spacing, exp2 units
    const float s15   = 15.0f * inv_rng;              // y = (w-mn)*s15 in (0,15)
    const float b15   = -mn * s15;
    const float rng15 = rng * (1.0f / 15.0f);

    half2_t G2[8];
#pragma unroll
    for (int i = 0; i < 8; ++i) G2[i] = (half2_t){(_Float16)0, (_Float16)0};

    // level constants {1-2i, -2i}, pinned in VGPRs (block remat inside loop)
    half2_t A2[8];
#pragma unroll
    for (int i = 0; i < 8; ++i) {
        A2[i] = (half2_t){(_Float16)(1 - 2 * i), (_Float16)(-2 * i)};
        asm("" : "+v"(A2[i]));
    }

    const float* __restrict__ wp = weight  + (size_t)r0 * COLS + c;
    float* __restrict__       dq = dequant + (size_t)r0 * COLS + c;

    for (int r = 0; r < RPB; r += UNROLL) {
        float w[UNROLL];
#pragma unroll
        for (int j = 0; j < UNROLL; ++j)
            w[j] = wp[(size_t)(r + j) * COLS];

#pragma unroll
        for (int j = 0; j < UNROLL; ++j) {
            const float y  = fmaf(w[j], s15, b15);    // in (0,15)
            float kf = floorf(y);
            kf = fminf(fmaxf(kf, 0.0f), 14.0f);       // v_med3

            const float q  = fmaf(y - kf, 2.0f * S, -S);   // (2f-S), exp2 units
            const float e  = __builtin_amdgcn_exp2f(q);
            const float uv = e * __builtin_amdgcn_rcpf(1.0f + e);  // u/(t+u)

            // dq = (kf - C2P + uv*C1PP)*rng15 + mn  (phantom +/-1 folded)
            __builtin_nontemporal_store(
                fmaf(fmaf(uv, C1PP, kf - C2P), rng15, mn),
                &dq[(size_t)(r + j) * COLS]);

            const float Pr = kf + uv;                 // (the +1 lives in A2)
            const _Float16 Ph = (_Float16)Pr;
            const half2_t P2 = {Ph, Ph};
#pragma unroll
            for (int i = 0; i < 8; ++i) {
                half2_t d;
                // d = clamp01(P2 + A2[i])  -- one VOP3P with clamp bit
                asm("v_pk_add_f16 %0, %1, %2 clamp"
                    : "=v"(d) : "v"(P2), "v"(A2[i]));
                G2[i] += d;                           // v_pk_add_f16
            }
        }
    }

    // difference the suffix sums -> bins, store fp16 partials
    float g[17];
#pragma unroll
    for (int l = 0; l < NLEV; ++l) g[l] = (float)G2[l >> 1][l & 1];
    g[16] = 0.0f;

    half8_t v0, v1;
#pragma unroll
    for (int l = 0; l < NLEV; ++l) {
        const float bin = g[l] - g[l + 1];
        if (l < 8) v0[l] = (_Float16)bin; else v1[l - 8] = (_Float16)bin;
    }
    half8_t* pp = (half8_t*)(partial + ((size_t)blockIdx.y * COLS + c) * NLEV);
    pp[0] = v0;
    pp[1] = v1;
}

// fused reduce + entropy: one thread per (col, level-pair) = 16384 threads,
// 256 blocks x 64 threads (one wave per block, max CU spread).
// 8 consecutive lanes own one column -> shuffle for the column total;
// full-wave butterfly for the block's entropy sum -> 1 atomic per block.
__global__ __launch_bounds__(64) void reduce_entropy_kernel(
    const _Float16* __restrict__ partial,
    float* __restrict__ out_ent)
{
    const int i = blockIdx.x * 64 + threadIdx.x;     // [0, COLS*NLEV/2)
    const half2_t* p2 = (const half2_t*)partial;

    float m0 = 0.0f, m1 = 0.0f;
#pragma unroll 32
    for (int rb = 0; rb < RBLKS; ++rb) {
        const half2_t v = p2[(size_t)rb * (COLS * NLEV / 2) + i];
        m0 += (float)v[0];
        m1 += (float)v[1];
    }

    float tot = m0 + m1;
    tot += __shfl_xor(tot, 1);
    tot += __shfl_xor(tot, 2);
    tot += __shfl_xor(tot, 4);          // column total across the 8-lane group
    const float inv = __builtin_amdgcn_rcpf(tot + EPS);

    const float p0 = m0 * inv;
    const float p1 = m1 * inv;
    float ent = -(p0 * __logf(p0 + EPS) + p1 * __logf(p1 + EPS));

    // 64-lane butterfly sum of per-(col,pair) entropy contributions
    ent += __shfl_xor(ent, 1);
    ent += __shfl_xor(ent, 2);
    ent += __shfl_xor(ent, 4);
    ent += __shfl_xor(ent, 8);
    ent += __shfl_xor(ent, 16);
    ent += __shfl_xor(ent, 32);

    if (threadIdx.x == 0) atomicAdd(out_ent, ent);   // 256 atomics total
}

extern "C" void kernel_launch(void* const* d_in, const int* in_sizes, int n_in,
                              void* d_out, int out_size, void* d_ws, size_t ws_size,
                              hipStream_t stream)
{
    const float* weight = (const float*)d_in[0];
    const float* w_min  = (const float*)d_in[1];
    const float* w_max  = (const float*)d_in[2];

    float* out     = (float*)d_out;
    float* dequant = out;                          // ROWS*COLS floats
    float* out_ent = out + (size_t)ROWS * COLS;    // 1 float
    _Float16* partial = (_Float16*)d_ws;           // RBLKS*COLS*NLEV halves

    quant_main_kernel<<<dim3(COLS / TPB, RBLKS), TPB, 0, stream>>>(
        weight, w_min, w_max, dequant, partial, out_ent);

    reduce_entropy_kernel<<<(COLS * NLEV / 2) / 64, 64, 0, stream>>>(
        partial, out_ent);
}